// Round 1
// 441.771 us; speedup vs baseline: 1.0053x; 1.0053x over previous
//
#include <hip/hip_runtime.h>

#define B_DIM 128
#define T_DIM 512
#define H_DIM 1024
#define O_DIM 256

typedef short bf16x8 __attribute__((ext_vector_type(8)));
typedef float f32x4 __attribute__((ext_vector_type(4)));

__device__ __forceinline__ unsigned short f2bf(float f) {
    union { float f; unsigned u; } v; v.f = f;
    unsigned u = v.u;
    u += 0x7fffu + ((u >> 16) & 1u);   // round-to-nearest-even
    return (unsigned short)(u >> 16);
}

// truncating bf16 pack of two floats via one v_perm_b32: D = [hi16(b) : hi16(a)]
__device__ __forceinline__ unsigned tpk(float a, float b) {
    union { float f; unsigned u; } x{a}, y{b};
    return __builtin_amdgcn_perm(y.u, x.u, 0x07060302u);
}

__device__ __forceinline__ void async16(const void* g, void* l) {
    __builtin_amdgcn_global_load_lds(
        (const __attribute__((address_space(1))) unsigned int*)g,
        (__attribute__((address_space(3))) unsigned int*)l, 16, 0, 0);
}

// ---- W[H][O] f32 -> Wt_tiled bf16, pre-tiled to the GEMM's exact LDS image ----
// Wt_tiled[nb 2][kc 32][kq 4][row 128][8]:  element (o,h) ->
//   (o>>7)*131072 + (h>>5)*4096 + ((h>>3)&3)*1024 + (o&127)*8 + (h&7)
__global__ __launch_bounds__(256) void transpose_w(const float* __restrict__ W,
                                                   unsigned short* __restrict__ Wt) {
    __shared__ float tile[32][33];
    int h0 = blockIdx.x * 32;
    int o0 = blockIdx.y * 32;
    int tx = threadIdx.x;   // 32
    int ty = threadIdx.y;   // 8
#pragma unroll
    for (int j = 0; j < 32; j += 8)
        tile[ty + j][tx] = W[(size_t)(h0 + ty + j) * O_DIM + o0 + tx];
    __syncthreads();
    int h = h0 + tx;
#pragma unroll
    for (int j = 0; j < 32; j += 8) {
        int o = o0 + ty + j;
        size_t idx = (size_t)(o >> 7) * 131072 + (size_t)(h >> 5) * 4096 +
                     (size_t)((h >> 3) & 3) * 1024 + (size_t)(o & 127) * 8 + (h & 7);
        Wt[idx] = f2bf(tile[tx][ty + j]);
    }
}

// ---------------- GEMM: h2[M=65536][256](bf16) = x[M][1024] @ W ---------------
// 128x128 tile, BK=32, bf16 MFMA 16x16x32, double-buffered LDS.
// A: coalesced float4 loads (8 lines/instr, fully consumed) + v_perm trunc-pack.
// B: global_load_lds width=16 from PRE-TILED Wt (global addrs = base + tid*16,
//    fully contiguous -> 8 consecutive lines/instr, no scatter).
// Block swizzle: the two blocks sharing an A-panel (nb=0/1 of the same mb) are
// placed at dispatch slots d and d+8 within a group of 16, so under round-robin
// workgroup->XCD assignment (d%8) they land on the SAME XCD and share each
// 16 KB A k-chunk through that XCD's L2 -> A fetched from HBM once, not twice.
__global__ __launch_bounds__(256, 4) void gemm_bf16(const float* __restrict__ x,
                                                    const unsigned short* __restrict__ Wtt,
                                                    unsigned short* __restrict__ h2) {
    __shared__ __align__(16) unsigned short As[2][128 * 40];    // 20 KiB
    __shared__ __align__(16) unsigned short Bs[2][4096];        // 16 KiB

    const int tid  = threadIdx.x;
    const int d    = blockIdx.x;
    const int mb   = (d >> 4) * 8 + (d & 7);   // XCD-pairing swizzle
    const int nb   = (d >> 3) & 1;
    const int m0   = mb * 128, n0 = nb * 128;
    const int lane = tid & 63;
    const int wave = tid >> 6;
    const int wm   = wave >> 1, wn = wave & 1;   // 2x2 waves, 64x64 each
    const int rowsel = lane & 15, quad = lane >> 4;

    // A coalesced staging coords: instr i covers rows wave*32+i*8..+8,
    // lanes 0..7 cover one full 128-B line per row.
    const int arow = wave * 32 + (lane >> 3);
    const int akf  = (lane & 7) * 4;
    const float* ag = x + (size_t)(m0 + arow) * H_DIM + akf;
    const int aoff = arow * 40 + akf;

    // B staging from pre-tiled Wt: per k-chunk an 8-KB contiguous image.
    const unsigned short* bg = Wtt + (size_t)nb * 131072 + (size_t)tid * 8;
    unsigned short* bl0 = (unsigned short*)&Bs[0][tid * 8];
    unsigned short* bl1 = (unsigned short*)&Bs[1][tid * 8];

    f32x4 acc[4][4];
#pragma unroll
    for (int i = 0; i < 4; ++i)
#pragma unroll
        for (int j = 0; j < 4; ++j)
            acc[i][j] = (f32x4){0.f, 0.f, 0.f, 0.f};

    // ---- prologue: stage k=0 into buf 0 ----
    {
        float4 a[4];
#pragma unroll
        for (int i = 0; i < 4; ++i)
            a[i] = *(const float4*)(ag + (size_t)i * 8 * H_DIM);
        async16(bg, bl0);
        async16(bg + 2048, bl0 + 2048);
#pragma unroll
        for (int i = 0; i < 4; ++i) {
            uint2 p;
            p.x = tpk(a[i].x, a[i].y);
            p.y = tpk(a[i].z, a[i].w);
            *(uint2*)&As[0][aoff + i * 8 * 40] = p;
        }
    }

    for (int k = 0; k < 32; ++k) {
        const int cur = k & 1, nxt = cur ^ 1;
        __syncthreads();   // buf[cur] committed (vmcnt/lgkm drained here)

        float4 a[4];
        if (k + 1 < 32) {
            const float* agk = ag + (size_t)(k + 1) * 32;
#pragma unroll
            for (int i = 0; i < 4; ++i)
                a[i] = *(const float4*)(agk + (size_t)i * 8 * H_DIM);
            const unsigned short* bgk = bg + (size_t)(k + 1) * 4096;
            unsigned short* bl = nxt ? bl1 : bl0;
            async16(bgk, bl);
            async16(bgk + 2048, bl + 2048);
        }

        bf16x8 af[4], bfr[4];
#pragma unroll
        for (int i = 0; i < 4; ++i) {
            af[i]  = *(const bf16x8*)&As[cur][(wm * 64 + rowsel + i * 16) * 40 + quad * 8];
            bfr[i] = *(const bf16x8*)&Bs[cur][quad * 1024 + (wn * 64 + rowsel + i * 16) * 8];
        }
#pragma unroll
        for (int i = 0; i < 4; ++i)
#pragma unroll
            for (int j = 0; j < 4; ++j)
                acc[i][j] = __builtin_amdgcn_mfma_f32_16x16x32_bf16(af[i], bfr[j], acc[i][j], 0, 0, 0);

        if (k + 1 < 32) {
#pragma unroll
            for (int i = 0; i < 4; ++i) {
                uint2 p;
                p.x = tpk(a[i].x, a[i].y);
                p.y = tpk(a[i].z, a[i].w);
                *(uint2*)&As[nxt][aoff + i * 8 * 40] = p;
            }
        }
    }

    // epilogue: C/D layout col=lane&15, row=quad*4+reg; store bf16
#pragma unroll
    for (int i = 0; i < 4; ++i) {
#pragma unroll
        for (int j = 0; j < 4; ++j) {
            int gm = m0 + wm * 64 + i * 16 + quad * 4;
            int gn = n0 + wn * 64 + j * 16 + rowsel;
            unsigned short* cp = h2 + (size_t)gm * O_DIM + gn;
            cp[0 * O_DIM] = f2bf(acc[i][j][0]);
            cp[1 * O_DIM] = f2bf(acc[i][j][1]);
            cp[2 * O_DIM] = f2bf(acc[i][j][2]);
            cp[3 * O_DIM] = f2bf(acc[i][j][3]);
        }
    }
}

// ---------------- chunked leaky-integrate + softmax accumulate ----------------
// alpha^64 = 1.6e-3 -> 64-step warmup; h2 in bf16; 4-deep prefetch ring.
__global__ __launch_bounds__(64) void snn_scan(const unsigned short* __restrict__ h2,
                                               float* __restrict__ out) {
    const int b = blockIdx.x >> 3;
    const int c = blockIdx.x & 7;
    const int t_start = c * 64;
    const int t_end   = min(t_start + 64, T_DIM - 1);  // 511 steps total
    const int s0      = max(0, t_start - 64);
    const int lane    = threadIdx.x;

    const float A   = 0.90483741803595957f;
    const float OMA = 0.09516258196404043f;

    const unsigned short* base = h2 + (size_t)b * T_DIM * O_DIM + lane * 4;
#define LD(row) (*(const uint2*)(base + (size_t)(row) * O_DIM))

    float4 mem = {0.f, 0.f, 0.f, 0.f};
    float4 acc = {0.f, 0.f, 0.f, 0.f};

    uint2 u0 = LD(s0), u1 = LD(s0 + 1), u2 = LD(s0 + 2), u3 = LD(s0 + 3);

    const int nIter = (t_end - s0 + 3) & ~3;

#define STEP(U, T)                                                              \
    {                                                                           \
        union { unsigned u; float f; } l0, h0, l1, h1;                          \
        l0.u = (U).x << 16; h0.u = (U).x & 0xffff0000u;                         \
        l1.u = (U).y << 16; h1.u = (U).y & 0xffff0000u;                         \
        mem.x = A * mem.x + OMA * l0.f;                                         \
        mem.y = A * mem.y + OMA * h0.f;                                         \
        mem.z = A * mem.z + OMA * l1.f;                                         \
        mem.w = A * mem.w + OMA * h1.f;                                         \
        if ((T) >= t_start && (T) < t_end) {                                    \
            float e0 = __expf(mem.x), e1 = __expf(mem.y);                       \
            float e2 = __expf(mem.z), e3 = __expf(mem.w);                       \
            float s = e0 + e1 + e2 + e3;                                        \
            s += __shfl_xor(s, 1);                                              \
            s += __shfl_xor(s, 2);                                              \
            s += __shfl_xor(s, 4);                                              \
            s += __shfl_xor(s, 8);                                              \
            s += __shfl_xor(s, 16);                                             \
            s += __shfl_xor(s, 32);                                             \
            float inv = 1.0f / s;                                               \
            acc.x += e0 * inv; acc.y += e1 * inv;                               \
            acc.z += e2 * inv; acc.w += e3 * inv;                               \
        }                                                                       \
    }

    for (int t = s0; t < s0 + nIter; t += 4) {
        STEP(u0, t);     u0 = LD(min(t + 4, T_DIM - 1));
        STEP(u1, t + 1); u1 = LD(min(t + 5, T_DIM - 1));
        STEP(u2, t + 2); u2 = LD(min(t + 6, T_DIM - 1));
        STEP(u3, t + 3); u3 = LD(min(t + 7, T_DIM - 1));
    }
#undef STEP
#undef LD

    float* op = out + b * O_DIM + lane * 4;
    atomicAdd(op + 0, acc.x);
    atomicAdd(op + 1, acc.y);
    atomicAdd(op + 2, acc.z);
    atomicAdd(op + 3, acc.w);
}

extern "C" void kernel_launch(void* const* d_in, const int* in_sizes, int n_in,
                              void* d_out, int out_size, void* d_ws, size_t ws_size,
                              hipStream_t stream) {
    const float* x = (const float*)d_in[0];
    const float* W = (const float*)d_in[1];
    float* out = (float*)d_out;

    unsigned short* h2 = (unsigned short*)d_ws;                  // 32 MiB (bf16)
    unsigned short* Wt = (unsigned short*)((char*)d_ws +
                         (size_t)B_DIM * T_DIM * O_DIM * sizeof(unsigned short));

    hipMemsetAsync(d_out, 0, (size_t)B_DIM * O_DIM * sizeof(float), stream);
    transpose_w<<<dim3(H_DIM / 32, O_DIM / 32), dim3(32, 8), 0, stream>>>(W, Wt);
    gemm_bf16<<<dim3((B_DIM * T_DIM / 128) * 2), 256, 0, stream>>>(x, Wt, h2);
    snn_scan<<<dim3(B_DIM * 8), 64, 0, stream>>>(h2, out);
}

// Round 2
// 433.454 us; speedup vs baseline: 1.0246x; 1.0192x over previous
//
#include <hip/hip_runtime.h>

#define B_DIM 128
#define T_DIM 512
#define H_DIM 1024
#define O_DIM 256

typedef short bf16x8 __attribute__((ext_vector_type(8)));
typedef float f32x4 __attribute__((ext_vector_type(4)));

__device__ __forceinline__ unsigned short f2bf(float f) {
    union { float f; unsigned u; } v; v.f = f;
    unsigned u = v.u;
    u += 0x7fffu + ((u >> 16) & 1u);   // round-to-nearest-even
    return (unsigned short)(u >> 16);
}

// truncating bf16 pack of two floats via one v_perm_b32: D = [hi16(b) : hi16(a)]
__device__ __forceinline__ unsigned tpk(float a, float b) {
    union { float f; unsigned u; } x{a}, y{b};
    return __builtin_amdgcn_perm(y.u, x.u, 0x07060302u);
}

__device__ __forceinline__ void async16(const void* g, void* l) {
    __builtin_amdgcn_global_load_lds(
        (const __attribute__((address_space(1))) unsigned int*)g,
        (__attribute__((address_space(3))) unsigned int*)l, 16, 0, 0);
}

// ---- W[H][O] f32 -> Wt_tiled bf16, pre-tiled to the GEMM's exact LDS image ----
// Wt_tiled[nb 2][kc 32][kq 4][row 128][8]:  element (o,h) ->
//   (o>>7)*131072 + (h>>5)*4096 + ((h>>3)&3)*1024 + (o&127)*8 + (h&7)
__global__ __launch_bounds__(256) void transpose_w(const float* __restrict__ W,
                                                   unsigned short* __restrict__ Wt) {
    __shared__ float tile[32][33];
    int h0 = blockIdx.x * 32;
    int o0 = blockIdx.y * 32;
    int tx = threadIdx.x;   // 32
    int ty = threadIdx.y;   // 8
#pragma unroll
    for (int j = 0; j < 32; j += 8)
        tile[ty + j][tx] = W[(size_t)(h0 + ty + j) * O_DIM + o0 + tx];
    __syncthreads();
    int h = h0 + tx;
#pragma unroll
    for (int j = 0; j < 32; j += 8) {
        int o = o0 + ty + j;
        size_t idx = (size_t)(o >> 7) * 131072 + (size_t)(h >> 5) * 4096 +
                     (size_t)((h >> 3) & 3) * 1024 + (size_t)(o & 127) * 8 + (h & 7);
        Wt[idx] = f2bf(tile[tx][ty + j]);
    }
}

// ---------------- GEMM: h2[M=65536][256](bf16) = x[M][1024] @ W ---------------
// 128x256 tile (FULL N), BK=32, bf16 MFMA 16x16x32, double-buffered LDS.
// 512 threads = 8 waves (2 wm x 4 wn), each wave owns a 64x64 sub-tile.
// Merging the two N-halves into one block means each A-panel of x is fetched
// from HBM exactly ONCE (deterministic, no reliance on XCD/L2 co-scheduling):
// x traffic 536 MB -> 268 MB, and the GEMM's BW floor drops to ~48 us.
// A: coalesced float4 loads (1 float4/thread/row-group; 64 rows/instr) + v_perm
//    trunc-pack into As (LDA=40 shorts, conflict-benign as before).
// B: global_load_lds width=16 from PRE-TILED Wt, both nb images per k-chunk
//    (2 async16/thread), LDS image [nb 2][kq 4][row 128][8] -- byte-identical
//    per-nb layout to the verified 128x128 version.
__global__ __launch_bounds__(512, 4) void gemm_bf16(const float* __restrict__ x,
                                                    const unsigned short* __restrict__ Wtt,
                                                    unsigned short* __restrict__ h2) {
    __shared__ __align__(16) unsigned short As[2][128 * 40];    // 20 KiB
    __shared__ __align__(16) unsigned short Bs[2][8192];        // 32 KiB

    const int tid  = threadIdx.x;
    const int mb   = blockIdx.x;
    const int m0   = mb * 128;
    const int lane = tid & 63;
    const int wave = tid >> 6;                   // 0..7
    const int wm   = wave >> 2, wn = wave & 3;   // 2x4 waves, 64x64 each
    const int rowsel = lane & 15, quad = lane >> 4;

    // A coalesced staging coords: instr i (i=0,1) covers rows i*64 + (tid>>3),
    // lanes 0..7 cover one full 128-B line per row.
    const int arow = tid >> 3;          // 0..63
    const int akf  = (tid & 7) * 4;
    const float* ag = x + (size_t)(m0 + arow) * H_DIM + akf;
    const int aoff = arow * 40 + akf;

    // B staging from pre-tiled Wt: per k-chunk two 8-KB contiguous images.
    const unsigned short* bg0 = Wtt + (size_t)tid * 8;
    const unsigned short* bg1 = Wtt + 131072 + (size_t)tid * 8;

    f32x4 acc[4][4];
#pragma unroll
    for (int i = 0; i < 4; ++i)
#pragma unroll
        for (int j = 0; j < 4; ++j)
            acc[i][j] = (f32x4){0.f, 0.f, 0.f, 0.f};

    // ---- prologue: stage k=0 into buf 0 ----
    {
        float4 a0 = *(const float4*)(ag);
        float4 a1 = *(const float4*)(ag + (size_t)64 * H_DIM);
        unsigned short* bl = &Bs[0][tid * 8];
        async16(bg0, bl);
        async16(bg1, bl + 4096);
        uint2 p0, p1;
        p0.x = tpk(a0.x, a0.y); p0.y = tpk(a0.z, a0.w);
        p1.x = tpk(a1.x, a1.y); p1.y = tpk(a1.z, a1.w);
        *(uint2*)&As[0][aoff] = p0;
        *(uint2*)&As[0][aoff + 64 * 40] = p1;
    }

    const int nbsel = wn >> 1;                 // which 8-KB B image this wave reads
    const int bbase = nbsel * 4096 + quad * 1024;
    const int bcol0 = (wn & 1) * 64 + rowsel;  // o & 127 for j=0

    for (int k = 0; k < 32; ++k) {
        const int cur = k & 1, nxt = cur ^ 1;
        __syncthreads();   // buf[cur] committed (vmcnt/lgkm drained here)

        float4 a0, a1;
        if (k + 1 < 32) {
            const float* agk = ag + (size_t)(k + 1) * 32;
            a0 = *(const float4*)(agk);
            a1 = *(const float4*)(agk + (size_t)64 * H_DIM);
            const size_t bko = (size_t)(k + 1) * 4096;
            unsigned short* bl = &Bs[nxt][tid * 8];
            async16(bg0 + bko, bl);
            async16(bg1 + bko, bl + 4096);
        }

        bf16x8 af[4], bfr[4];
#pragma unroll
        for (int i = 0; i < 4; ++i) {
            af[i]  = *(const bf16x8*)&As[cur][(wm * 64 + rowsel + i * 16) * 40 + quad * 8];
            bfr[i] = *(const bf16x8*)&Bs[cur][bbase + (bcol0 + i * 16) * 8];
        }
#pragma unroll
        for (int i = 0; i < 4; ++i)
#pragma unroll
            for (int j = 0; j < 4; ++j)
                acc[i][j] = __builtin_amdgcn_mfma_f32_16x16x32_bf16(af[i], bfr[j], acc[i][j], 0, 0, 0);

        if (k + 1 < 32) {
            uint2 p0, p1;
            p0.x = tpk(a0.x, a0.y); p0.y = tpk(a0.z, a0.w);
            p1.x = tpk(a1.x, a1.y); p1.y = tpk(a1.z, a1.w);
            *(uint2*)&As[nxt][aoff] = p0;
            *(uint2*)&As[nxt][aoff + 64 * 40] = p1;
        }
    }

    // epilogue: C/D layout col=lane&15, row=quad*4+reg; store bf16
#pragma unroll
    for (int i = 0; i < 4; ++i) {
#pragma unroll
        for (int j = 0; j < 4; ++j) {
            int gm = m0 + wm * 64 + i * 16 + quad * 4;
            int gn = wn * 64 + j * 16 + rowsel;
            unsigned short* cp = h2 + (size_t)gm * O_DIM + gn;
            cp[0 * O_DIM] = f2bf(acc[i][j][0]);
            cp[1 * O_DIM] = f2bf(acc[i][j][1]);
            cp[2 * O_DIM] = f2bf(acc[i][j][2]);
            cp[3 * O_DIM] = f2bf(acc[i][j][3]);
        }
    }
}

// ---------------- chunked leaky-integrate + softmax accumulate ----------------
// alpha^64 = 1.6e-3 -> 64-step warmup; h2 in bf16; 4-deep prefetch ring.
__global__ __launch_bounds__(64) void snn_scan(const unsigned short* __restrict__ h2,
                                               float* __restrict__ out) {
    const int b = blockIdx.x >> 3;
    const int c = blockIdx.x & 7;
    const int t_start = c * 64;
    const int t_end   = min(t_start + 64, T_DIM - 1);  // 511 steps total
    const int s0      = max(0, t_start - 64);
    const int lane    = threadIdx.x;

    const float A   = 0.90483741803595957f;
    const float OMA = 0.09516258196404043f;

    const unsigned short* base = h2 + (size_t)b * T_DIM * O_DIM + lane * 4;
#define LD(row) (*(const uint2*)(base + (size_t)(row) * O_DIM))

    float4 mem = {0.f, 0.f, 0.f, 0.f};
    float4 acc = {0.f, 0.f, 0.f, 0.f};

    uint2 u0 = LD(s0), u1 = LD(s0 + 1), u2 = LD(s0 + 2), u3 = LD(s0 + 3);

    const int nIter = (t_end - s0 + 3) & ~3;

#define STEP(U, T)                                                              \
    {                                                                           \
        union { unsigned u; float f; } l0, h0, l1, h1;                          \
        l0.u = (U).x << 16; h0.u = (U).x & 0xffff0000u;                         \
        l1.u = (U).y << 16; h1.u = (U).y & 0xffff0000u;                         \
        mem.x = A * mem.x + OMA * l0.f;                                         \
        mem.y = A * mem.y + OMA * h0.f;                                         \
        mem.z = A * mem.z + OMA * l1.f;                                         \
        mem.w = A * mem.w + OMA * h1.f;                                         \
        if ((T) >= t_start && (T) < t_end) {                                    \
            float e0 = __expf(mem.x), e1 = __expf(mem.y);                       \
            float e2 = __expf(mem.z), e3 = __expf(mem.w);                       \
            float s = e0 + e1 + e2 + e3;                                        \
            s += __shfl_xor(s, 1);                                              \
            s += __shfl_xor(s, 2);                                              \
            s += __shfl_xor(s, 4);                                              \
            s += __shfl_xor(s, 8);                                              \
            s += __shfl_xor(s, 16);                                             \
            s += __shfl_xor(s, 32);                                             \
            float inv = 1.0f / s;                                               \
            acc.x += e0 * inv; acc.y += e1 * inv;                               \
            acc.z += e2 * inv; acc.w += e3 * inv;                               \
        }                                                                       \
    }

    for (int t = s0; t < s0 + nIter; t += 4) {
        STEP(u0, t);     u0 = LD(min(t + 4, T_DIM - 1));
        STEP(u1, t + 1); u1 = LD(min(t + 5, T_DIM - 1));
        STEP(u2, t + 2); u2 = LD(min(t + 6, T_DIM - 1));
        STEP(u3, t + 3); u3 = LD(min(t + 7, T_DIM - 1));
    }
#undef STEP
#undef LD

    float* op = out + b * O_DIM + lane * 4;
    atomicAdd(op + 0, acc.x);
    atomicAdd(op + 1, acc.y);
    atomicAdd(op + 2, acc.z);
    atomicAdd(op + 3, acc.w);
}

extern "C" void kernel_launch(void* const* d_in, const int* in_sizes, int n_in,
                              void* d_out, int out_size, void* d_ws, size_t ws_size,
                              hipStream_t stream) {
    const float* x = (const float*)d_in[0];
    const float* W = (const float*)d_in[1];
    float* out = (float*)d_out;

    unsigned short* h2 = (unsigned short*)d_ws;                  // 32 MiB (bf16)
    unsigned short* Wt = (unsigned short*)((char*)d_ws +
                         (size_t)B_DIM * T_DIM * O_DIM * sizeof(unsigned short));

    hipMemsetAsync(d_out, 0, (size_t)B_DIM * O_DIM * sizeof(float), stream);
    transpose_w<<<dim3(H_DIM / 32, O_DIM / 32), dim3(32, 8), 0, stream>>>(W, Wt);
    gemm_bf16<<<dim3(B_DIM * T_DIM / 128), 512, 0, stream>>>(x, Wt, h2);
    snn_scan<<<dim3(B_DIM * 8), 64, 0, stream>>>(h2, out);
}

// Round 3
// 430.765 us; speedup vs baseline: 1.0310x; 1.0062x over previous
//
#include <hip/hip_runtime.h>

#define B_DIM 128
#define T_DIM 512
#define H_DIM 1024
#define O_DIM 256

typedef short bf16x8 __attribute__((ext_vector_type(8)));
typedef float f32x4 __attribute__((ext_vector_type(4)));

__device__ __forceinline__ unsigned short f2bf(float f) {
    union { float f; unsigned u; } v; v.f = f;
    unsigned u = v.u;
    u += 0x7fffu + ((u >> 16) & 1u);   // round-to-nearest-even
    return (unsigned short)(u >> 16);
}

// truncating bf16 pack of two floats via one v_perm_b32: D = [hi16(b) : hi16(a)]
__device__ __forceinline__ unsigned tpk(float a, float b) {
    union { float f; unsigned u; } x{a}, y{b};
    return __builtin_amdgcn_perm(y.u, x.u, 0x07060302u);
}

__device__ __forceinline__ void async16(const void* g, void* l) {
    __builtin_amdgcn_global_load_lds(
        (const __attribute__((address_space(1))) unsigned int*)g,
        (__attribute__((address_space(3))) unsigned int*)l, 16, 0, 0);
}

#define SB() __builtin_amdgcn_sched_barrier(0)

// ---- W[H][O] f32 -> Wt_tiled bf16, pre-tiled to the GEMM's exact LDS image ----
// Wt_tiled[nb 2][kc 32][kq 4][row 128][8]:  element (o,h) ->
//   (o>>7)*131072 + (h>>5)*4096 + ((h>>3)&3)*1024 + (o&127)*8 + (h&7)
// Also zeroes the output accumulator (blocks with blockIdx.x==0), replacing the
// separate hipMemsetAsync dispatch.
__global__ __launch_bounds__(256) void transpose_w(const float* __restrict__ W,
                                                   unsigned short* __restrict__ Wt,
                                                   float* __restrict__ out) {
    __shared__ float tile[32][33];
    if (blockIdx.x == 0) {
        // 8 blocks * 256 threads zero 128*256 f32 = 8192 float4
        int t = blockIdx.y * 256 + threadIdx.y * 32 + threadIdx.x;
        float4 z = {0.f, 0.f, 0.f, 0.f};
        float4* o4 = (float4*)out;
#pragma unroll
        for (int i = 0; i < 4; ++i) o4[t * 4 + i] = z;
    }
    int h0 = blockIdx.x * 32;
    int o0 = blockIdx.y * 32;
    int tx = threadIdx.x;   // 32
    int ty = threadIdx.y;   // 8
#pragma unroll
    for (int j = 0; j < 32; j += 8)
        tile[ty + j][tx] = W[(size_t)(h0 + ty + j) * O_DIM + o0 + tx];
    __syncthreads();
    int h = h0 + tx;
#pragma unroll
    for (int j = 0; j < 32; j += 8) {
        int o = o0 + ty + j;
        size_t idx = (size_t)(o >> 7) * 131072 + (size_t)(h >> 5) * 4096 +
                     (size_t)((h >> 3) & 3) * 1024 + (size_t)(o & 127) * 8 + (h & 7);
        Wt[idx] = f2bf(tile[tx][ty + j]);
    }
}

// ---------------- GEMM: h2[M=65536][256](bf16) = x[M][1024] @ W ---------------
// 128x256 tile (FULL N), BK=32, bf16 MFMA 16x16x32.
// NEW: 3-deep LDS buffers + RAW s_barrier + COUNTED vmcnt (T3/T4 mechanism).
// __syncthreads' implicit vmcnt(0) drained the just-issued next-tile
// global_load_lds every K-step (~900cy HBM latency vs ~500cy of compute to
// hide it). Now: B loads for tile k+1 are issued at iter k and waited with
// vmcnt(2) at iter-k end (A-loads for tile k+2 stay in flight across the
// barrier); A register loads live 2 iterations. sched_barrier(0) pins VMEM
// issue order so the counted waits are exact; lgkmcnt(0) precedes every
// barrier (covers the As ds_writes).
// Hazard audit: tile k+1 is written into buf[(k+1)%3], whose previous
// occupant (tile k-2) was consumed at iter k-2 -> >=2 barriers separate
// consumption from overwrite. Race-free by construction.
__global__ __launch_bounds__(512, 4) void gemm_bf16(const float* __restrict__ x,
                                                    const unsigned short* __restrict__ Wtt,
                                                    unsigned short* __restrict__ h2) {
    __shared__ __align__(16) unsigned short As[3][128 * 40];    // 30 KiB
    __shared__ __align__(16) unsigned short Bs[3][8192];        // 48 KiB

    const int tid  = threadIdx.x;
    const int mb   = blockIdx.x;
    const int m0   = mb * 128;
    const int lane = tid & 63;
    const int wave = tid >> 6;                   // 0..7
    const int wm   = wave >> 2, wn = wave & 3;   // 2x4 waves, 64x64 each
    const int rowsel = lane & 15, quad = lane >> 4;

    // A coalesced staging coords: instr i (i=0,1) covers rows i*64 + (tid>>3),
    // lanes 0..7 cover one full 128-B line per row.
    const int arow = tid >> 3;          // 0..63
    const int akf  = (tid & 7) * 4;
    const float* ag = x + (size_t)(m0 + arow) * H_DIM + akf;
    const int aoff = arow * 40 + akf;

    // B staging from pre-tiled Wt: per k-chunk two 8-KB contiguous images.
    const unsigned short* bg0 = Wtt + (size_t)tid * 8;
    const unsigned short* bg1 = Wtt + 131072 + (size_t)tid * 8;

    f32x4 acc[4][4];
#pragma unroll
    for (int i = 0; i < 4; ++i)
#pragma unroll
        for (int j = 0; j < 4; ++j)
            acc[i][j] = (f32x4){0.f, 0.f, 0.f, 0.f};

    const int nbsel = wn >> 1;                 // which 8-KB B image this wave reads
    const int bbase = nbsel * 4096 + quad * 1024;
    const int bcol0 = (wn & 1) * 64 + rowsel;  // o & 127 for j=0

    float4 aX0, aX1;   // A data for the NEXT tile to be packed into LDS

    // ---- prologue: tile 0 fully staged; tile 1 A-loads + B-loads in flight ----
    {
        float4 t0 = *(const float4*)(ag);
        float4 t1 = *(const float4*)(ag + (size_t)64 * H_DIM);
        SB();
        async16(bg0, &Bs[0][tid * 8]);                   // B(0)
        async16(bg1, &Bs[0][tid * 8 + 4096]);
        SB();
        aX0 = *(const float4*)(ag + 32);                 // A(1)
        aX1 = *(const float4*)(ag + 32 + (size_t)64 * H_DIM);
        SB();
        uint2 p0, p1;                                    // pack A(0) -> As[0]
        p0.x = tpk(t0.x, t0.y); p0.y = tpk(t0.z, t0.w);
        p1.x = tpk(t1.x, t1.y); p1.y = tpk(t1.z, t1.w);
        *(uint2*)&As[0][aoff] = p0;
        *(uint2*)&As[0][aoff + 64 * 40] = p1;
        asm volatile("s_waitcnt vmcnt(2)" ::: "memory"); // B(0) landed; A(1) flying
        asm volatile("s_waitcnt lgkmcnt(0)" ::: "memory");
        __builtin_amdgcn_s_barrier();
        SB();
    }

    // ---- steady state: k = 0..29, constant vmcnt counts ----
    for (int k = 0; k < 30; ++k) {
        const int cur = k % 3, nxt = (k + 1) % 3;

        const size_t bko = (size_t)(k + 1) * 4096;
        async16(bg0 + bko, &Bs[nxt][tid * 8]);           // B(k+1)
        async16(bg1 + bko, &Bs[nxt][tid * 8 + 4096]);
        SB();
        const float* agk = ag + (size_t)(k + 2) * 32;    // A(k+2)
        float4 t0 = *(const float4*)(agk);
        float4 t1 = *(const float4*)(agk + (size_t)64 * H_DIM);
        SB();

        bf16x8 af[4], bfr[4];
#pragma unroll
        for (int i = 0; i < 4; ++i) {
            af[i]  = *(const bf16x8*)&As[cur][(wm * 64 + rowsel + i * 16) * 40 + quad * 8];
            bfr[i] = *(const bf16x8*)&Bs[cur][bbase + (bcol0 + i * 16) * 8];
        }
#pragma unroll
        for (int i = 0; i < 4; ++i)
#pragma unroll
            for (int j = 0; j < 4; ++j)
                acc[i][j] = __builtin_amdgcn_mfma_f32_16x16x32_bf16(af[i], bfr[j], acc[i][j], 0, 0, 0);

        // pack A(k+1) -> As[nxt]; aX regs were loaded 1 iter ago (long done)
        {
            uint2 p0, p1;
            p0.x = tpk(aX0.x, aX0.y); p0.y = tpk(aX0.z, aX0.w);
            p1.x = tpk(aX1.x, aX1.y); p1.y = tpk(aX1.z, aX1.w);
            *(uint2*)&As[nxt][aoff] = p0;
            *(uint2*)&As[nxt][aoff + 64 * 40] = p1;
        }
        aX0 = t0; aX1 = t1;

        asm volatile("s_waitcnt vmcnt(2)" ::: "memory"); // B(k+1) landed; A(k+2) flying
        asm volatile("s_waitcnt lgkmcnt(0)" ::: "memory");
        __builtin_amdgcn_s_barrier();
        SB();
    }

    // ---- peeled k=30: last B issue, no A issue ----
    {
        const size_t bko = (size_t)31 * 4096;
        async16(bg0 + bko, &Bs[1][tid * 8]);             // B(31) -> buf[31%3=1]
        async16(bg1 + bko, &Bs[1][tid * 8 + 4096]);
        SB();

        bf16x8 af[4], bfr[4];
#pragma unroll
        for (int i = 0; i < 4; ++i) {
            af[i]  = *(const bf16x8*)&As[0][(wm * 64 + rowsel + i * 16) * 40 + quad * 8];
            bfr[i] = *(const bf16x8*)&Bs[0][bbase + (bcol0 + i * 16) * 8];
        }
#pragma unroll
        for (int i = 0; i < 4; ++i)
#pragma unroll
            for (int j = 0; j < 4; ++j)
                acc[i][j] = __builtin_amdgcn_mfma_f32_16x16x32_bf16(af[i], bfr[j], acc[i][j], 0, 0, 0);

        uint2 p0, p1;                                    // pack A(31) -> As[1]
        p0.x = tpk(aX0.x, aX0.y); p0.y = tpk(aX0.z, aX0.w);
        p1.x = tpk(aX1.x, aX1.y); p1.y = tpk(aX1.z, aX1.w);
        *(uint2*)&As[1][aoff] = p0;
        *(uint2*)&As[1][aoff + 64 * 40] = p1;

        asm volatile("s_waitcnt vmcnt(0)" ::: "memory"); // everything landed
        asm volatile("s_waitcnt lgkmcnt(0)" ::: "memory");
        __builtin_amdgcn_s_barrier();
        SB();
    }

    // ---- peeled k=31: compute only ----
    {
        bf16x8 af[4], bfr[4];
#pragma unroll
        for (int i = 0; i < 4; ++i) {
            af[i]  = *(const bf16x8*)&As[1][(wm * 64 + rowsel + i * 16) * 40 + quad * 8];
            bfr[i] = *(const bf16x8*)&Bs[1][bbase + (bcol0 + i * 16) * 8];
        }
#pragma unroll
        for (int i = 0; i < 4; ++i)
#pragma unroll
            for (int j = 0; j < 4; ++j)
                acc[i][j] = __builtin_amdgcn_mfma_f32_16x16x32_bf16(af[i], bfr[j], acc[i][j], 0, 0, 0);
    }

    // epilogue: C/D layout col=lane&15, row=quad*4+reg; store bf16
#pragma unroll
    for (int i = 0; i < 4; ++i) {
#pragma unroll
        for (int j = 0; j < 4; ++j) {
            int gm = m0 + wm * 64 + i * 16 + quad * 4;
            int gn = wn * 64 + j * 16 + rowsel;
            unsigned short* cp = h2 + (size_t)gm * O_DIM + gn;
            cp[0 * O_DIM] = f2bf(acc[i][j][0]);
            cp[1 * O_DIM] = f2bf(acc[i][j][1]);
            cp[2 * O_DIM] = f2bf(acc[i][j][2]);
            cp[3 * O_DIM] = f2bf(acc[i][j][3]);
        }
    }
}

// ---------------- chunked leaky-integrate + softmax accumulate ----------------
// alpha^64 = 1.6e-3 -> 64-step warmup; h2 in bf16; 4-deep prefetch ring.
__global__ __launch_bounds__(64) void snn_scan(const unsigned short* __restrict__ h2,
                                               float* __restrict__ out) {
    const int b = blockIdx.x >> 3;
    const int c = blockIdx.x & 7;
    const int t_start = c * 64;
    const int t_end   = min(t_start + 64, T_DIM - 1);  // 511 steps total
    const int s0      = max(0, t_start - 64);
    const int lane    = threadIdx.x;

    const float A   = 0.90483741803595957f;
    const float OMA = 0.09516258196404043f;

    const unsigned short* base = h2 + (size_t)b * T_DIM * O_DIM + lane * 4;
#define LD(row) (*(const uint2*)(base + (size_t)(row) * O_DIM))

    float4 mem = {0.f, 0.f, 0.f, 0.f};
    float4 acc = {0.f, 0.f, 0.f, 0.f};

    uint2 u0 = LD(s0), u1 = LD(s0 + 1), u2 = LD(s0 + 2), u3 = LD(s0 + 3);

    const int nIter = (t_end - s0 + 3) & ~3;

#define STEP(U, T)                                                              \
    {                                                                           \
        union { unsigned u; float f; } l0, h0, l1, h1;                          \
        l0.u = (U).x << 16; h0.u = (U).x & 0xffff0000u;                         \
        l1.u = (U).y << 16; h1.u = (U).y & 0xffff0000u;                         \
        mem.x = A * mem.x + OMA * l0.f;                                         \
        mem.y = A * mem.y + OMA * h0.f;                                         \
        mem.z = A * mem.z + OMA * l1.f;                                         \
        mem.w = A * mem.w + OMA * h1.f;                                         \
        if ((T) >= t_start && (T) < t_end) {                                    \
            float e0 = __expf(mem.x), e1 = __expf(mem.y);                       \
            float e2 = __expf(mem.z), e3 = __expf(mem.w);                       \
            float s = e0 + e1 + e2 + e3;                                        \
            s += __shfl_xor(s, 1);                                              \
            s += __shfl_xor(s, 2);                                              \
            s += __shfl_xor(s, 4);                                              \
            s += __shfl_xor(s, 8);                                              \
            s += __shfl_xor(s, 16);                                             \
            s += __shfl_xor(s, 32);                                             \
            float inv = 1.0f / s;                                               \
            acc.x += e0 * inv; acc.y += e1 * inv;                               \
            acc.z += e2 * inv; acc.w += e3 * inv;                               \
        }                                                                       \
    }

    for (int t = s0; t < s0 + nIter; t += 4) {
        STEP(u0, t);     u0 = LD(min(t + 4, T_DIM - 1));
        STEP(u1, t + 1); u1 = LD(min(t + 5, T_DIM - 1));
        STEP(u2, t + 2); u2 = LD(min(t + 6, T_DIM - 1));
        STEP(u3, t + 3); u3 = LD(min(t + 7, T_DIM - 1));
    }
#undef STEP
#undef LD

    float* op = out + b * O_DIM + lane * 4;
    atomicAdd(op + 0, acc.x);
    atomicAdd(op + 1, acc.y);
    atomicAdd(op + 2, acc.z);
    atomicAdd(op + 3, acc.w);
}

extern "C" void kernel_launch(void* const* d_in, const int* in_sizes, int n_in,
                              void* d_out, int out_size, void* d_ws, size_t ws_size,
                              hipStream_t stream) {
    const float* x = (const float*)d_in[0];
    const float* W = (const float*)d_in[1];
    float* out = (float*)d_out;

    unsigned short* h2 = (unsigned short*)d_ws;                  // 32 MiB (bf16)
    unsigned short* Wt = (unsigned short*)((char*)d_ws +
                         (size_t)B_DIM * T_DIM * O_DIM * sizeof(unsigned short));

    transpose_w<<<dim3(H_DIM / 32, O_DIM / 32), dim3(32, 8), 0, stream>>>(W, Wt, out);
    gemm_bf16<<<dim3(B_DIM * T_DIM / 128), 512, 0, stream>>>(x, Wt, h2);
    snn_scan<<<dim3(B_DIM * 8), 64, 0, stream>>>(h2, out);
}

// Round 4
// 409.003 us; speedup vs baseline: 1.0859x; 1.0532x over previous
//
#include <hip/hip_runtime.h>

#define B_DIM 128
#define T_DIM 512
#define H_DIM 1024
#define O_DIM 256

typedef short bf16x8 __attribute__((ext_vector_type(8)));
typedef float f32x4 __attribute__((ext_vector_type(4)));

__device__ __forceinline__ unsigned short f2bf(float f) {
    union { float f; unsigned u; } v; v.f = f;
    unsigned u = v.u;
    u += 0x7fffu + ((u >> 16) & 1u);   // round-to-nearest-even
    return (unsigned short)(u >> 16);
}

// truncating bf16 pack of two floats via one v_perm_b32: D = [hi16(b) : hi16(a)]
__device__ __forceinline__ unsigned tpk(float a, float b) {
    union { float f; unsigned u; } x{a}, y{b};
    return __builtin_amdgcn_perm(y.u, x.u, 0x07060302u);
}

__device__ __forceinline__ void async16(const void* g, void* l) {
    __builtin_amdgcn_global_load_lds(
        (const __attribute__((address_space(1))) unsigned int*)g,
        (__attribute__((address_space(3))) unsigned int*)l, 16, 0, 0);
}

#define SB() __builtin_amdgcn_sched_barrier(0)

// ---- W[H][O] f32 -> Wt_tiled bf16, pre-tiled to the GEMM's exact LDS image ----
// Wt_tiled[nb 2][kc 32][kq 4][row 128][8]:  element (o,h) ->
//   (o>>7)*131072 + (h>>5)*4096 + ((h>>3)&3)*1024 + (o&127)*8 + (h&7)
// Also zeroes the output accumulator (blocks with blockIdx.x==0), replacing the
// separate hipMemsetAsync dispatch.
__global__ __launch_bounds__(256) void transpose_w(const float* __restrict__ W,
                                                   unsigned short* __restrict__ Wt,
                                                   float* __restrict__ out) {
    __shared__ float tile[32][33];
    if (blockIdx.x == 0) {
        // 8 blocks * 256 threads zero 128*256 f32 = 8192 float4
        int t = blockIdx.y * 256 + threadIdx.y * 32 + threadIdx.x;
        float4 z = {0.f, 0.f, 0.f, 0.f};
        float4* o4 = (float4*)out;
#pragma unroll
        for (int i = 0; i < 4; ++i) o4[t * 4 + i] = z;
    }
    int h0 = blockIdx.x * 32;
    int o0 = blockIdx.y * 32;
    int tx = threadIdx.x;   // 32
    int ty = threadIdx.y;   // 8
#pragma unroll
    for (int j = 0; j < 32; j += 8)
        tile[ty + j][tx] = W[(size_t)(h0 + ty + j) * O_DIM + o0 + tx];
    __syncthreads();
    int h = h0 + tx;
#pragma unroll
    for (int j = 0; j < 32; j += 8) {
        int o = o0 + ty + j;
        size_t idx = (size_t)(o >> 7) * 131072 + (size_t)(h >> 5) * 4096 +
                     (size_t)((h >> 3) & 3) * 1024 + (size_t)(o & 127) * 8 + (h & 7);
        Wt[idx] = f2bf(tile[tx][ty + j]);
    }
}

// ---------------- GEMM: h2[M=65536][256](bf16) = x[M][1024] @ W ---------------
// 128x256 tile (FULL N), BK=32, bf16 MFMA 16x16x32.
// 3-deep LDS buffers + RAW s_barrier + COUNTED vmcnt (T3/T4 mechanism).
// B loads for tile k+1 issued at iter k, waited with vmcnt(2) at iter-k end
// (A-loads for tile k+2 stay in flight across the barrier); A register loads
// live 2 iterations. sched_barrier(0) pins VMEM issue order; lgkmcnt(0)
// precedes every barrier. Hazard audit: buffer overwrite is separated from
// its previous consumption by >=2 barriers. Race-free by construction.
__global__ __launch_bounds__(512, 4) void gemm_bf16(const float* __restrict__ x,
                                                    const unsigned short* __restrict__ Wtt,
                                                    unsigned short* __restrict__ h2) {
    __shared__ __align__(16) unsigned short As[3][128 * 40];    // 30 KiB
    __shared__ __align__(16) unsigned short Bs[3][8192];        // 48 KiB

    const int tid  = threadIdx.x;
    const int mb   = blockIdx.x;
    const int m0   = mb * 128;
    const int lane = tid & 63;
    const int wave = tid >> 6;                   // 0..7
    const int wm   = wave >> 2, wn = wave & 3;   // 2x4 waves, 64x64 each
    const int rowsel = lane & 15, quad = lane >> 4;

    // A coalesced staging coords: instr i (i=0,1) covers rows i*64 + (tid>>3),
    // lanes 0..7 cover one full 128-B line per row.
    const int arow = tid >> 3;          // 0..63
    const int akf  = (tid & 7) * 4;
    const float* ag = x + (size_t)(m0 + arow) * H_DIM + akf;
    const int aoff = arow * 40 + akf;

    // B staging from pre-tiled Wt: per k-chunk two 8-KB contiguous images.
    const unsigned short* bg0 = Wtt + (size_t)tid * 8;
    const unsigned short* bg1 = Wtt + 131072 + (size_t)tid * 8;

    f32x4 acc[4][4];
#pragma unroll
    for (int i = 0; i < 4; ++i)
#pragma unroll
        for (int j = 0; j < 4; ++j)
            acc[i][j] = (f32x4){0.f, 0.f, 0.f, 0.f};

    const int nbsel = wn >> 1;                 // which 8-KB B image this wave reads
    const int bbase = nbsel * 4096 + quad * 1024;
    const int bcol0 = (wn & 1) * 64 + rowsel;  // o & 127 for j=0

    float4 aX0, aX1;   // A data for the NEXT tile to be packed into LDS

    // ---- prologue: tile 0 fully staged; tile 1 A-loads + B-loads in flight ----
    {
        float4 t0 = *(const float4*)(ag);
        float4 t1 = *(const float4*)(ag + (size_t)64 * H_DIM);
        SB();
        async16(bg0, &Bs[0][tid * 8]);                   // B(0)
        async16(bg1, &Bs[0][tid * 8 + 4096]);
        SB();
        aX0 = *(const float4*)(ag + 32);                 // A(1)
        aX1 = *(const float4*)(ag + 32 + (size_t)64 * H_DIM);
        SB();
        uint2 p0, p1;                                    // pack A(0) -> As[0]
        p0.x = tpk(t0.x, t0.y); p0.y = tpk(t0.z, t0.w);
        p1.x = tpk(t1.x, t1.y); p1.y = tpk(t1.z, t1.w);
        *(uint2*)&As[0][aoff] = p0;
        *(uint2*)&As[0][aoff + 64 * 40] = p1;
        asm volatile("s_waitcnt vmcnt(2)" ::: "memory"); // B(0) landed; A(1) flying
        asm volatile("s_waitcnt lgkmcnt(0)" ::: "memory");
        __builtin_amdgcn_s_barrier();
        SB();
    }

    // ---- steady state: k = 0..29, constant vmcnt counts ----
    for (int k = 0; k < 30; ++k) {
        const int cur = k % 3, nxt = (k + 1) % 3;

        const size_t bko = (size_t)(k + 1) * 4096;
        async16(bg0 + bko, &Bs[nxt][tid * 8]);           // B(k+1)
        async16(bg1 + bko, &Bs[nxt][tid * 8 + 4096]);
        SB();
        const float* agk = ag + (size_t)(k + 2) * 32;    // A(k+2)
        float4 t0 = *(const float4*)(agk);
        float4 t1 = *(const float4*)(agk + (size_t)64 * H_DIM);
        SB();

        bf16x8 af[4], bfr[4];
#pragma unroll
        for (int i = 0; i < 4; ++i) {
            af[i]  = *(const bf16x8*)&As[cur][(wm * 64 + rowsel + i * 16) * 40 + quad * 8];
            bfr[i] = *(const bf16x8*)&Bs[cur][bbase + (bcol0 + i * 16) * 8];
        }
#pragma unroll
        for (int i = 0; i < 4; ++i)
#pragma unroll
            for (int j = 0; j < 4; ++j)
                acc[i][j] = __builtin_amdgcn_mfma_f32_16x16x32_bf16(af[i], bfr[j], acc[i][j], 0, 0, 0);

        // pack A(k+1) -> As[nxt]; aX regs were loaded 1 iter ago (long done)
        {
            uint2 p0, p1;
            p0.x = tpk(aX0.x, aX0.y); p0.y = tpk(aX0.z, aX0.w);
            p1.x = tpk(aX1.x, aX1.y); p1.y = tpk(aX1.z, aX1.w);
            *(uint2*)&As[nxt][aoff] = p0;
            *(uint2*)&As[nxt][aoff + 64 * 40] = p1;
        }
        aX0 = t0; aX1 = t1;

        asm volatile("s_waitcnt vmcnt(2)" ::: "memory"); // B(k+1) landed; A(k+2) flying
        asm volatile("s_waitcnt lgkmcnt(0)" ::: "memory");
        __builtin_amdgcn_s_barrier();
        SB();
    }

    // ---- peeled k=30: last B issue, no A issue ----
    {
        const size_t bko = (size_t)31 * 4096;
        async16(bg0 + bko, &Bs[1][tid * 8]);             // B(31) -> buf[31%3=1]
        async16(bg1 + bko, &Bs[1][tid * 8 + 4096]);
        SB();

        bf16x8 af[4], bfr[4];
#pragma unroll
        for (int i = 0; i < 4; ++i) {
            af[i]  = *(const bf16x8*)&As[0][(wm * 64 + rowsel + i * 16) * 40 + quad * 8];
            bfr[i] = *(const bf16x8*)&Bs[0][bbase + (bcol0 + i * 16) * 8];
        }
#pragma unroll
        for (int i = 0; i < 4; ++i)
#pragma unroll
            for (int j = 0; j < 4; ++j)
                acc[i][j] = __builtin_amdgcn_mfma_f32_16x16x32_bf16(af[i], bfr[j], acc[i][j], 0, 0, 0);

        uint2 p0, p1;                                    // pack A(31) -> As[1]
        p0.x = tpk(aX0.x, aX0.y); p0.y = tpk(aX0.z, aX0.w);
        p1.x = tpk(aX1.x, aX1.y); p1.y = tpk(aX1.z, aX1.w);
        *(uint2*)&As[1][aoff] = p0;
        *(uint2*)&As[1][aoff + 64 * 40] = p1;

        asm volatile("s_waitcnt vmcnt(0)" ::: "memory"); // everything landed
        asm volatile("s_waitcnt lgkmcnt(0)" ::: "memory");
        __builtin_amdgcn_s_barrier();
        SB();
    }

    // ---- peeled k=31: compute only ----
    {
        bf16x8 af[4], bfr[4];
#pragma unroll
        for (int i = 0; i < 4; ++i) {
            af[i]  = *(const bf16x8*)&As[1][(wm * 64 + rowsel + i * 16) * 40 + quad * 8];
            bfr[i] = *(const bf16x8*)&Bs[1][bbase + (bcol0 + i * 16) * 8];
        }
#pragma unroll
        for (int i = 0; i < 4; ++i)
#pragma unroll
            for (int j = 0; j < 4; ++j)
                acc[i][j] = __builtin_amdgcn_mfma_f32_16x16x32_bf16(af[i], bfr[j], acc[i][j], 0, 0, 0);
    }

    // epilogue: C/D layout col=lane&15, row=quad*4+reg; store bf16
#pragma unroll
    for (int i = 0; i < 4; ++i) {
#pragma unroll
        for (int j = 0; j < 4; ++j) {
            int gm = m0 + wm * 64 + i * 16 + quad * 4;
            int gn = wn * 64 + j * 16 + rowsel;
            unsigned short* cp = h2 + (size_t)gm * O_DIM + gn;
            cp[0 * O_DIM] = f2bf(acc[i][j][0]);
            cp[1 * O_DIM] = f2bf(acc[i][j][1]);
            cp[2 * O_DIM] = f2bf(acc[i][j][2]);
            cp[3 * O_DIM] = f2bf(acc[i][j][3]);
        }
    }
}

// ---------------- chunked leaky-integrate + softmax accumulate ----------------
// alpha^64 = 1.6e-3 -> 64-step warmup; h2 in bf16; 4-deep prefetch ring.
// R3: (1) warmup/active split into guard-free loops -> the 4 unrolled STEP
// chains live in one basic block and their reduce latencies overlap;
// (2) 64-lane sum via 4 DPP adds (quad_perm x2, row_half_mirror, row_mirror)
// + ds_swizzle xor16 + one shfl_xor(32): ~70cy chain vs ~170cy of 6 serial
// ds-shuffles. All-lanes-valid tree: xor1, xor2, ^7-mirror(sum8), ^15-mirror
// (sum16), xor16 (sum32, swizzle is 32-lane-local), xor32 (bpermute).
__global__ __launch_bounds__(64) void snn_scan(const unsigned short* __restrict__ h2,
                                               float* __restrict__ out) {
    const int b = blockIdx.x >> 3;
    const int c = blockIdx.x & 7;
    const int t_start = c * 64;
    const int t_end   = min(t_start + 64, T_DIM - 1);  // 511 steps total
    const int s0      = max(0, t_start - 64);
    const int lane    = threadIdx.x;

    const float A   = 0.90483741803595957f;
    const float OMA = 0.09516258196404043f;

    const unsigned short* base = h2 + (size_t)b * T_DIM * O_DIM + lane * 4;
#define LD(row) (*(const uint2*)(base + (size_t)(row) * O_DIM))

    float4 mem = {0.f, 0.f, 0.f, 0.f};
    float4 acc = {0.f, 0.f, 0.f, 0.f};

    uint2 u0 = LD(s0), u1 = LD(s0 + 1), u2 = LD(s0 + 2), u3 = LD(s0 + 3);

#define DPP_ADD(s, ctrl)                                                        \
    { union { float f; int i; } _u; _u.f = (s);                                 \
      _u.i = __builtin_amdgcn_update_dpp(0, _u.i, ctrl, 0xF, 0xF, true);        \
      (s) += _u.f; }

#define MEMUP(U)                                                                \
    {                                                                           \
        union { unsigned u; float f; } l0, h0, l1, h1;                          \
        l0.u = (U).x << 16; h0.u = (U).x & 0xffff0000u;                         \
        l1.u = (U).y << 16; h1.u = (U).y & 0xffff0000u;                         \
        mem.x = A * mem.x + OMA * l0.f;                                         \
        mem.y = A * mem.y + OMA * h0.f;                                         \
        mem.z = A * mem.z + OMA * l1.f;                                         \
        mem.w = A * mem.w + OMA * h1.f;                                         \
    }

#define ASTEP(U)                                                                \
    {                                                                           \
        MEMUP(U)                                                                \
        float e0 = __expf(mem.x), e1 = __expf(mem.y);                           \
        float e2 = __expf(mem.z), e3 = __expf(mem.w);                           \
        float s = e0 + e1 + e2 + e3;                                            \
        DPP_ADD(s, 0xB1)   /* xor1  (quad_perm [1,0,3,2]) */                    \
        DPP_ADD(s, 0x4E)   /* xor2  (quad_perm [2,3,0,1]) */                    \
        DPP_ADD(s, 0x141)  /* ^7  row_half_mirror -> sum8  */                   \
        DPP_ADD(s, 0x140)  /* ^15 row_mirror      -> sum16 */                   \
        { union { float f; int i; } _u; _u.f = s;                               \
          _u.i = __builtin_amdgcn_ds_swizzle(_u.i, 0x401F); s += _u.f; }        \
        s += __shfl_xor(s, 32);                                                 \
        float inv = 1.0f / s;                                                   \
        acc.x += e0 * inv; acc.y += e1 * inv;                                   \
        acc.z += e2 * inv; acc.w += e3 * inv;                                   \
    }

    // warmup: [s0, t_start), length 64 (c>0) or 0 (c=0) -- no softmax, no guard
    for (int t = s0; t < t_start; t += 4) {
        MEMUP(u0); u0 = LD(t + 4);
        MEMUP(u1); u1 = LD(t + 5);
        MEMUP(u2); u2 = LD(t + 6);
        MEMUP(u3); u3 = LD(t + 7);
    }

    // active: [t_start, t_end) -- full quads, guard-free straight-line body
    const int nfull = (t_end - t_start) & ~3;   // 64 (c<7) or 60 (c=7)
    for (int t = t_start; t < t_start + nfull; t += 4) {
        ASTEP(u0); u0 = LD(min(t + 4, T_DIM - 1));
        ASTEP(u1); u1 = LD(min(t + 5, T_DIM - 1));
        ASTEP(u2); u2 = LD(min(t + 6, T_DIM - 1));
        ASTEP(u3); u3 = LD(min(t + 7, T_DIM - 1));
    }

    // remainder (c=7 only: 3 steps on rows 508..510, already in u0..u2)
    const int rem = (t_end - t_start) & 3;
    if (rem > 0) ASTEP(u0);
    if (rem > 1) ASTEP(u1);
    if (rem > 2) ASTEP(u2);

#undef ASTEP
#undef MEMUP
#undef DPP_ADD
#undef LD

    float* op = out + b * O_DIM + lane * 4;
    atomicAdd(op + 0, acc.x);
    atomicAdd(op + 1, acc.y);
    atomicAdd(op + 2, acc.z);
    atomicAdd(op + 3, acc.w);
}

extern "C" void kernel_launch(void* const* d_in, const int* in_sizes, int n_in,
                              void* d_out, int out_size, void* d_ws, size_t ws_size,
                              hipStream_t stream) {
    const float* x = (const float*)d_in[0];
    const float* W = (const float*)d_in[1];
    float* out = (float*)d_out;

    unsigned short* h2 = (unsigned short*)d_ws;                  // 32 MiB (bf16)
    unsigned short* Wt = (unsigned short*)((char*)d_ws +
                         (size_t)B_DIM * T_DIM * O_DIM * sizeof(unsigned short));

    transpose_w<<<dim3(H_DIM / 32, O_DIM / 32), dim3(32, 8), 0, stream>>>(W, Wt, out);
    gemm_bf16<<<dim3(B_DIM * T_DIM / 128), 512, 0, stream>>>(x, Wt, h2);
    snn_scan<<<dim3(B_DIM * 8), 64, 0, stream>>>(h2, out);
}